// Round 17
// baseline (243.721 us; speedup 1.0000x reference)
//
#include <hip/hip_runtime.h>
#include <hip/hip_bf16.h>
#include <math.h>

#define BB 256
#define TT 64
#define EE 2048
#define DD 512
#define AA 512
#define VV 10000
#define VPAD 10240               // 80 * 128
#define EMBD 256
#define KLSTM (EE + EMBD + DD)   // 2816
#define N4D (4 * DD)             // 2048
#define MROWS (BB * TT)          // 16384

using bf16x8 = __attribute__((ext_vector_type(8))) __bf16;
using f32x4  = __attribute__((ext_vector_type(4))) float;

#define GLL16(gp, lp) __builtin_amdgcn_global_load_lds( \
    (const __attribute__((address_space(1))) void*)(gp), \
    (__attribute__((address_space(3))) void*)(lp), 16, 0, 0)

__device__ __forceinline__ float sigf(float x) { return 1.f / (1.f + expf(-x)); }

// ======== fused weight transposes: w2t | wxh_t | wpt (register-uniform) ========
__global__ void k_wt(const float* __restrict__ w2, const float* __restrict__ wx,
                     const float* __restrict__ wh, const float* __restrict__ wp,
                     __bf16* __restrict__ w2t, __bf16* __restrict__ wxh_t,
                     __bf16* __restrict__ wpt) {
    __shared__ float t[32][33];
    const int bid = blockIdx.x;
    const int tid = threadIdx.x;
    const int tx = tid & 31, ty = tid >> 5;   // 32 x 8

    if (bid < 1024) {                         // ---- w2t ----
        const int k0 = (bid & 63) * 32, n0 = (bid >> 6) * 32;
        #pragma unroll
        for (int i = 0; i < 4; ++i)
            t[ty + 8 * i][tx] = w2[(size_t)(k0 + ty + 8 * i) * AA + n0 + tx];
        __syncthreads();
        #pragma unroll
        for (int i = 0; i < 4; ++i)
            w2t[(size_t)(n0 + ty + 8 * i) * EE + k0 + tx] = (__bf16)t[tx][ty + 8 * i];
    } else if (bid < 6656) {                  // ---- wxh_t ----
        const int idx = bid - 1024;
        const int k0 = (idx % 88) * 32, n0 = (idx / 88) * 32;
        #pragma unroll
        for (int i = 0; i < 4; ++i) {
            int k = k0 + ty + 8 * i;
            const float* wrow = (k < EE + EMBD) ? &wx[(size_t)k * N4D]
                                                : &wh[(size_t)(k - EE - EMBD) * N4D];
            t[ty + 8 * i][tx] = wrow[n0 + tx];
        }
        __syncthreads();
        #pragma unroll
        for (int i = 0; i < 4; ++i)
            wxh_t[(size_t)(n0 + ty + 8 * i) * KLSTM + k0 + tx] = (__bf16)t[tx][ty + 8 * i];
    } else {                                  // ---- wpt ----
        const int idx = bid - 6656;
        const int k0 = (idx & 15) * 32, n0 = (idx >> 4) * 32;
        #pragma unroll
        for (int i = 0; i < 4; ++i) {
            int n = n0 + tx;
            t[ty + 8 * i][tx] = wp[(size_t)(k0 + ty + 8 * i) * VV + (n < VV ? n : VV - 1)];
        }
        __syncthreads();
        #pragma unroll
        for (int i = 0; i < 4; ++i)
            wpt[(size_t)(n0 + ty + 8 * i) * DD + k0 + tx] = (__bf16)t[tx][ty + 8 * i];
    }
}

// ---------------- q = hidden @ w1 + b1 + b2 (separate: own regalloc) ----------------
__global__ void k_q(const float* __restrict__ hidden, const float* __restrict__ w1,
                    const float* __restrict__ b1, const float* __restrict__ b2,
                    float* __restrict__ qq) {
    __shared__ float hs[DD];
    const int b = blockIdx.x, tid = threadIdx.x;
    {
        float2 hv = *(const float2*)&hidden[(size_t)b * DD + 2 * tid];
        hs[2 * tid] = hv.x; hs[2 * tid + 1] = hv.y;
    }
    __syncthreads();
    const int a0 = 2 * tid;
    float2 acc = {0.f, 0.f};
    #pragma unroll 4
    for (int k = 0; k < DD; ++k) {
        float2 w = *(const float2*)&w1[(size_t)k * AA + a0];
        float h = hs[k];
        acc.x = fmaf(h, w.x, acc.x);
        acc.y = fmaf(h, w.y, acc.y);
    }
    qq[(size_t)b * AA + a0]     = acc.x + b1[a0]     + b2[a0];
    qq[(size_t)b * AA + a0 + 1] = acc.y + b1[a0 + 1] + b2[a0 + 1];
}

// ---- score partial: spart[nb][m] = sum_{n in nb 64-slice} tanh(q+s)*v ----
// MAX-TLP variant: tile 64M x 64N, 256 thr = 4 waves (2x2, wave 32x32),
// LDS 16.5 KB, 8 blocks/CU (32 waves/CU). Grid 2048 flat mb-fastest: the 8
// nb-siblings of an mb co-reside on one CU -> enc HBM-read once, L1-shared.
// Same 2-barrier loop: B via global_load_lds (linear dest, pre-swizzled src,
// swizzled read), A reg-staged f32->bf16.
__global__ __launch_bounds__(256, 8) void k_score(
        const float* __restrict__ enc, const __bf16* __restrict__ w2t,
        const float* __restrict__ qq, const float* __restrict__ vvec,
        float* __restrict__ spart) {
    __shared__ bf16x8 Abuf[64][8];       // 8 KB [row][granule ^ (row&7)]
    __shared__ bf16x8 Bbuf[64][8];       // 8 KB [row][granule], DMA-written linear
    __shared__ float qsv[64], vsv[64], wredL[4][64];
    const int tid = threadIdx.x;
    const int mb = blockIdx.x & 255, nb = blockIdx.x >> 8;   // 256 mb x 8 nb
    const int m0 = mb * 64, n0 = nb * 64;                    // one batch b = mb
    const int l = tid & 63, wv = tid >> 6;                   // 4 waves
    const int wm = wv >> 1, wn = wv & 1;                     // wave tile 32m x 32n
    const int ar = l & 15, agr = l >> 4;

    if (tid < 64) qsv[tid] = qq[(size_t)mb * AA + n0 + tid];
    else if (tid < 128) vsv[tid - 64] = vvec[n0 + tid - 64];

    // A staging: 64 rows x 8 granules, 4 threads/row, 2 granules (16 f32) each
    const int arow = tid >> 2, ag0 = (tid & 3) * 2;
    const float* aptr = enc + (size_t)(m0 + arow) * EE + ag0 * 8;

    // B staging: wave wv, DMA i in {0,1} covers rows wv*16 + i*8 .. +7 (1 KB each)
    // lane l -> row_off l>>3, stored granule l&7; source granule (l&7)^(l>>3)
    const int brow0 = wv * 16;
    const __bf16* bsrc = w2t + (size_t)(n0 + brow0 + (l >> 3)) * EE
                             + ((l & 7) ^ (l >> 3)) * 8;

    f32x4 acc[2][2];
    #pragma unroll
    for (int mi = 0; mi < 2; ++mi)
        #pragma unroll
        for (int ni = 0; ni < 2; ++ni)
            acc[mi][ni] = (f32x4){0.f, 0.f, 0.f, 0.f};

    const int NIT = EE / 64;   // 32
    for (int it = 0; it < NIT; ++it) {
        if (it > 0) __syncthreads();           // previous tile fully consumed
        // B: 2 async 1KB DMAs per wave (8 total = 64x64 tile)
        #pragma unroll
        for (int i = 0; i < 2; ++i)
            GLL16(bsrc + (size_t)i * 8 * EE + it * 64, &Bbuf[brow0 + i * 8][0]);
        // A: 4 float4 -> 2 swizzled granules
        {
            float4 u0 = *(const float4*)(aptr + it * 64);
            float4 u1 = *(const float4*)(aptr + it * 64 + 4);
            float4 u2 = *(const float4*)(aptr + it * 64 + 8);
            float4 u3 = *(const float4*)(aptr + it * 64 + 12);
            bf16x8 pk;
            pk[0] = (__bf16)u0.x; pk[1] = (__bf16)u0.y; pk[2] = (__bf16)u0.z; pk[3] = (__bf16)u0.w;
            pk[4] = (__bf16)u1.x; pk[5] = (__bf16)u1.y; pk[6] = (__bf16)u1.z; pk[7] = (__bf16)u1.w;
            Abuf[arow][ag0 ^ (arow & 7)] = pk;
            pk[0] = (__bf16)u2.x; pk[1] = (__bf16)u2.y; pk[2] = (__bf16)u2.z; pk[3] = (__bf16)u2.w;
            pk[4] = (__bf16)u3.x; pk[5] = (__bf16)u3.y; pk[6] = (__bf16)u3.z; pk[7] = (__bf16)u3.w;
            Abuf[arow][(ag0 + 1) ^ (arow & 7)] = pk;
        }
        __syncthreads();                       // drains DMA vmcnt + lgkm
        #pragma unroll
        for (int ks = 0; ks < 2; ++ks) {
            bf16x8 afr[2], bfr[2];
            #pragma unroll
            for (int mi = 0; mi < 2; ++mi)
                afr[mi] = Abuf[wm * 32 + mi * 16 + ar][(ks * 4 + agr) ^ (ar & 7)];
            #pragma unroll
            for (int ni = 0; ni < 2; ++ni)
                bfr[ni] = Bbuf[wn * 32 + ni * 16 + ar][(ks * 4 + agr) ^ (ar & 7)];
            #pragma unroll
            for (int mi = 0; mi < 2; ++mi)
                #pragma unroll
                for (int ni = 0; ni < 2; ++ni)
                    acc[mi][ni] = __builtin_amdgcn_mfma_f32_16x16x32_bf16(afr[mi], bfr[ni], acc[mi][ni], 0, 0, 0);
        }
    }

    // epilogue: tanh(q + s) * v, reduce over this block's 64 n-cols
    float sred[2][4];
    #pragma unroll
    for (int mi = 0; mi < 2; ++mi)
        #pragma unroll
        for (int r = 0; r < 4; ++r) sred[mi][r] = 0.f;
    #pragma unroll
    for (int ni = 0; ni < 2; ++ni) {
        const int col = wn * 32 + ni * 16 + ar;
        const float qa = qsv[col], va = vsv[col];
        #pragma unroll
        for (int mi = 0; mi < 2; ++mi)
            #pragma unroll
            for (int r = 0; r < 4; ++r)
                sred[mi][r] += tanhf(qa + acc[mi][ni][r]) * va;
    }
    #pragma unroll
    for (int mi = 0; mi < 2; ++mi)
        #pragma unroll
        for (int r = 0; r < 4; ++r) {
            #pragma unroll
            for (int off = 1; off < 16; off <<= 1)
                sred[mi][r] += __shfl_xor(sred[mi][r], off, 64);
        }
    if (ar == 0) {
        #pragma unroll
        for (int mi = 0; mi < 2; ++mi)
            #pragma unroll
            for (int r = 0; r < 4; ++r)
                wredL[wv][wm * 0 + mi * 16 + agr * 4 + r] = 0.f;  // init not needed; direct write below
        #pragma unroll
        for (int mi = 0; mi < 2; ++mi)
            #pragma unroll
            for (int r = 0; r < 4; ++r)
                wredL[wv][wm * 32 + mi * 16 + agr * 4 + r] = sred[mi][r];
    }
    __syncthreads();
    if (tid < 64) {
        // rows 0..31 reduced by waves {wm=0}: wv 0 (wn0) + wv 1 (wn1);
        // rows 32..63 by wv 2 + wv 3. wredL[wv][row] valid only for that wave's wm.
        float s = (tid < 32) ? (wredL[0][tid] + wredL[1][tid])
                             : (wredL[2][tid] + wredL[3][tid]);
        spart[(size_t)nb * MROWS + m0 + tid] = s;
    }
}

// -------- softmax over t (from 8 partials) + context = sum_t attn * enc --------
__global__ void k_context(const float* __restrict__ enc, const float* __restrict__ spart,
                          const float* __restrict__ bv, float* __restrict__ ctx) {
    __shared__ float attn[TT];
    const int b = blockIdx.y;
    const int tid = threadIdx.x;
    if (tid < 64) {
        const int m = b * TT + tid;
        float s = bv[0];
        #pragma unroll
        for (int i = 0; i < 8; ++i) s += spart[(size_t)i * MROWS + m];
        float mx = s;
        #pragma unroll
        for (int off = 1; off < 64; off <<= 1) mx = fmaxf(mx, __shfl_xor(mx, off, 64));
        float p = expf(s - mx);
        float sum = p;
        #pragma unroll
        for (int off = 1; off < 64; off <<= 1) sum += __shfl_xor(sum, off, 64);
        attn[tid] = p / sum;
    }
    __syncthreads();
    const int e = blockIdx.x * 1024 + tid * 4;
    const float* encb = enc + (size_t)b * TT * EE + e;
    float4 acc = {0.f, 0.f, 0.f, 0.f};
    #pragma unroll 4
    for (int t = 0; t < TT; ++t) {
        float a = attn[t];
        float4 ev = *(const float4*)&encb[(size_t)t * EE];
        acc.x = fmaf(a, ev.x, acc.x);
        acc.y = fmaf(a, ev.y, acc.y);
        acc.z = fmaf(a, ev.z, acc.z);
        acc.w = fmaf(a, ev.w, acc.w);
    }
    *(float4*)&ctx[(size_t)b * EE + e] = acc;
}

// ------- z = [ctx, emb[c], hidden] @ [wx; wh] via bf16 MFMA, K split 4 ways -------
#define ZKS 4
#define ZKC (KLSTM / ZKS)    // 704
#define ZNIT (ZKC / 32)      // 22
__global__ void k_z(const float* __restrict__ ctx, const float* __restrict__ emb,
                    const int* __restrict__ cidx, const float* __restrict__ hidden,
                    const __bf16* __restrict__ wt, float* __restrict__ zp) {
    __shared__ bf16x8 Abuf[32][ZKC / 8];   // [row][granule], granule ^= row&7 (45 KB)
    __shared__ int cbs[32];
    const int tid = threadIdx.x;
    const int l = tid & 63, wv = tid >> 6;
    const int b0  = blockIdx.y * 32;
    const int kc0 = blockIdx.z * ZKC;
    const int nw  = blockIdx.x * 256 + wv * 64;

    if (tid < 32) cbs[tid] = cidx[b0 + tid];
    __syncthreads();

    {
        const int srow = tid >> 3, g0 = tid & 7;
        const int bg = b0 + srow;
        const int erow = cbs[srow];
        #pragma unroll
        for (int i = 0; i < 11; ++i) {
            int g = g0 + 8 * i;
            int k = kc0 + g * 8;
            const float* src;
            if (k < EE)             src = &ctx[(size_t)bg * EE + k];
            else if (k < EE + EMBD) src = &emb[(size_t)erow * EMBD + (k - EE)];
            else                    src = &hidden[(size_t)bg * DD + (k - EE - EMBD)];
            float4 u0 = *(const float4*)src;
            float4 u1 = *(const float4*)(src + 4);
            bf16x8 pk;
            pk[0] = (__bf16)u0.x; pk[1] = (__bf16)u0.y; pk[2] = (__bf16)u0.z; pk[3] = (__bf16)u0.w;
            pk[4] = (__bf16)u1.x; pk[5] = (__bf16)u1.y; pk[6] = (__bf16)u1.z; pk[7] = (__bf16)u1.w;
            Abuf[srow][g ^ (srow & 7)] = pk;
        }
    }
    __syncthreads();

    const int ar = l & 15, agr = l >> 4;
    const __bf16* bbase = wt + (size_t)(nw + ar) * KLSTM + kc0 + agr * 8;

    f32x4 acc[2][4];
    #pragma unroll
    for (int mt = 0; mt < 2; ++mt)
        #pragma unroll
        for (int f = 0; f < 4; ++f)
            acc[mt][f] = (f32x4){0.f, 0.f, 0.f, 0.f};

    bf16x8 bA[4], bBv[4];
    #pragma unroll
    for (int f = 0; f < 4; ++f)
        bA[f] = *(const bf16x8*)(bbase + (size_t)f * 16 * KLSTM);

    for (int itp = 0; itp < ZNIT / 2; ++itp) {
        const int it0 = 2 * itp, it1 = 2 * itp + 1;
        #pragma unroll
        for (int f = 0; f < 4; ++f)
            bBv[f] = *(const bf16x8*)(bbase + (size_t)f * 16 * KLSTM + it1 * 32);
        {
            bf16x8 a0 = Abuf[ar][(it0 * 4 + agr) ^ (ar & 7)];
            bf16x8 a1 = Abuf[16 + ar][(it0 * 4 + agr) ^ (ar & 7)];
            #pragma unroll
            for (int f = 0; f < 4; ++f) {
                acc[0][f] = __builtin_amdgcn_mfma_f32_16x16x32_bf16(a0, bA[f], acc[0][f], 0, 0, 0);
                acc[1][f] = __builtin_amdgcn_mfma_f32_16x16x32_bf16(a1, bA[f], acc[1][f], 0, 0, 0);
            }
        }
        const int it2 = (it1 + 1 < ZNIT) ? it1 + 1 : it1;
        #pragma unroll
        for (int f = 0; f < 4; ++f)
            bA[f] = *(const bf16x8*)(bbase + (size_t)f * 16 * KLSTM + it2 * 32);
        {
            bf16x8 a0 = Abuf[ar][(it1 * 4 + agr) ^ (ar & 7)];
            bf16x8 a1 = Abuf[16 + ar][(it1 * 4 + agr) ^ (ar & 7)];
            #pragma unroll
            for (int f = 0; f < 4; ++f) {
                acc[0][f] = __builtin_amdgcn_mfma_f32_16x16x32_bf16(a0, bBv[f], acc[0][f], 0, 0, 0);
                acc[1][f] = __builtin_amdgcn_mfma_f32_16x16x32_bf16(a1, bBv[f], acc[1][f], 0, 0, 0);
            }
        }
    }

    float* zpo = zp + (size_t)blockIdx.z * BB * N4D;
    #pragma unroll
    for (int mt = 0; mt < 2; ++mt)
        #pragma unroll
        for (int f = 0; f < 4; ++f)
            #pragma unroll
            for (int r = 0; r < 4; ++r)
                zpo[(size_t)(b0 + mt * 16 + agr * 4 + r) * N4D + nw + f * 16 + ar] = acc[mt][f][r];
}

// ---------------- LSTM gates: sum K-split partials + bias, then activations ----------------
__global__ void k_gates(const float* __restrict__ zp, const float* __restrict__ carry,
                        const float* __restrict__ bl,
                        float* __restrict__ hout, float* __restrict__ cout) {
    const int b = blockIdx.x, tid = threadIdx.x;
    const size_t P = (size_t)BB * N4D;
    #pragma unroll
    for (int r = 0; r < 2; ++r) {
        int d = tid + r * 256;
        float zi = bl[d], zf = bl[DD + d], zg = bl[2 * DD + d], zo = bl[3 * DD + d];
        #pragma unroll
        for (int ks = 0; ks < ZKS; ++ks) {
            const float* zb = zp + ks * P + (size_t)b * N4D;
            zi += zb[d];
            zf += zb[DD + d];
            zg += zb[2 * DD + d];
            zo += zb[3 * DD + d];
        }
        float c = carry[(size_t)b * DD + d];
        float cn = sigf(zf) * c + sigf(zi) * tanhf(zg);
        float hn = sigf(zo) * tanhf(cn);
        cout[(size_t)b * DD + d] = cn;
        hout[(size_t)b * DD + d] = hn;
    }
}

// ---------------- logits = h_new @ wp + bp  via bf16 MFMA ----------------
__global__ __launch_bounds__(256, 4) void k_logits(
        const float* __restrict__ hnew, const __bf16* __restrict__ wpt,
        const float* __restrict__ bp, float* __restrict__ logits) {
    __shared__ bf16x8 Abuf[64][8];
    __shared__ bf16x8 Bbuf[128][8];
    __shared__ float bps[128];
    const int tid = threadIdx.x;
    const int nb = blockIdx.x % 80, mb = blockIdx.x / 80;
    const int m0 = mb * 64, n0 = nb * 128;
    const int l = tid & 63, wv = tid >> 6;
    const int wm = wv >> 1, wn = wv & 1;
    const int ar = l & 15, agr = l >> 4;

    if (tid < 128) {
        int j = n0 + tid;
        bps[tid] = (j < VV) ? bp[j] : 0.f;
    }

    const int arow = tid >> 2, ag0 = (tid & 3) * 2;
    const float* aptr = hnew + (size_t)(m0 + arow) * DD + ag0 * 8;
    const int brow = tid >> 1, bg0 = (tid & 1) * 4;
    const __bf16* bptr = wpt + (size_t)(n0 + brow) * DD + bg0 * 8;

    f32x4 acc[2][4];
    #pragma unroll
    for (int mi = 0; mi < 2; ++mi)
        #pragma unroll
        for (int ni = 0; ni < 4; ++ni)
            acc[mi][ni] = (f32x4){0.f, 0.f, 0.f, 0.f};

    float4 af[4];
    bf16x8 bstg[4];
    #pragma unroll
    for (int j = 0; j < 4; ++j) af[j] = *(const float4*)(aptr + j * 4);
    #pragma unroll
    for (int i = 0; i < 4; ++i) bstg[i] = *(const bf16x8*)(bptr + i * 8);

    const int NIT = DD / 64;   // 8
    for (int it = 0; it < NIT; ++it) {
        if (it > 0) __syncthreads();
        {
            bf16x8 pk;
            pk[0] = (__bf16)af[0].x; pk[1] = (__bf16)af[0].y; pk[2] = (__bf16)af[0].z; pk[3] = (__bf16)af[0].w;
            pk[4] = (__bf16)af[1].x; pk[5] = (__bf16)af[1].y; pk[6] = (__bf16)af[1].z; pk[7] = (__bf16)af[1].w;
            Abuf[arow][ag0 ^ (arow & 7)] = pk;
            pk[0] = (__bf16)af[2].x; pk[1] = (__bf16)af[2].y; pk[2] = (__bf16)af[2].z; pk[3] = (__bf16)af[2].w;
            pk[4] = (__bf16)af[3].x; pk[5] = (__bf16)af[3].y; pk[6] = (__bf16)af[3].z; pk[7] = (__bf16)af[3].w;
            Abuf[arow][(ag0 + 1) ^ (arow & 7)] = pk;
        }
        #pragma unroll
        for (int i = 0; i < 4; ++i)
            Bbuf[brow][(bg0 + i) ^ (brow & 7)] = bstg[i];
        if (it + 1 < NIT) {
            const int k1 = (it + 1) * 64;
            #pragma unroll
            for (int j = 0; j < 4; ++j) af[j] = *(const float4*)(aptr + k1 + j * 4);
            #pragma unroll
            for (int i = 0; i < 4; ++i) bstg[i] = *(const bf16x8*)(bptr + k1 + i * 8);
        }
        __syncthreads();
        #pragma unroll
        for (int ks = 0; ks < 2; ++ks) {
            bf16x8 afr[2], bfr[4];
            #pragma unroll
            for (int mi = 0; mi < 2; ++mi)
                afr[mi] = Abuf[wm * 32 + mi * 16 + ar][(ks * 4 + agr) ^ (ar & 7)];
            #pragma unroll
            for (int ni = 0; ni < 4; ++ni)
                bfr[ni] = Bbuf[wn * 64 + ni * 16 + ar][(ks * 4 + agr) ^ (ar & 7)];
            #pragma unroll
            for (int mi = 0; mi < 2; ++mi)
                #pragma unroll
                for (int ni = 0; ni < 4; ++ni)
                    acc[mi][ni] = __builtin_amdgcn_mfma_f32_16x16x32_bf16(afr[mi], bfr[ni], acc[mi][ni], 0, 0, 0);
        }
    }

    #pragma unroll
    for (int mi = 0; mi < 2; ++mi)
        #pragma unroll
        for (int ni = 0; ni < 4; ++ni) {
            const int colL = wn * 64 + ni * 16 + ar;
            const int col = n0 + colL;
            if (col < VV) {
                const float bb = bps[colL];
                #pragma unroll
                for (int r = 0; r < 4; ++r) {
                    const int row = m0 + wm * 32 + mi * 16 + agr * 4 + r;
                    logits[(size_t)row * VV + col] = acc[mi][ni][r] + bb;
                }
            }
        }
}

extern "C" void kernel_launch(void* const* d_in, const int* in_sizes, int n_in,
                              void* d_out, int out_size, void* d_ws, size_t ws_size,
                              hipStream_t stream) {
    const int*   cidx   = (const int*)d_in[0];
    const float* hidden = (const float*)d_in[1];
    const float* carry  = (const float*)d_in[2];
    const float* enc    = (const float*)d_in[3];
    const float* emb    = (const float*)d_in[4];
    const float* w1     = (const float*)d_in[5];
    const float* b1     = (const float*)d_in[6];
    const float* w2     = (const float*)d_in[7];
    const float* b2     = (const float*)d_in[8];
    const float* vvec   = (const float*)d_in[9];
    const float* bv     = (const float*)d_in[10];
    const float* wx     = (const float*)d_in[11];
    const float* wh     = (const float*)d_in[12];
    const float* bl     = (const float*)d_in[13];
    const float* wp     = (const float*)d_in[14];
    const float* bp     = (const float*)d_in[15];

    float* out    = (float*)d_out;
    float* logits = out;
    float* hout   = out + (size_t)BB * VV;
    float* cout   = hout + (size_t)BB * DD;

    float* ws    = (float*)d_ws;
    float* qq    = ws;                          // B*A            = 131072 f32
    float* score = qq + (size_t)BB * AA;        // (layout keep)
    float* ctx   = score + (size_t)BB * TT;     // B*E            = 524288 f32
    float* zp    = ctx + (size_t)BB * EE;       // ZKS*B*4D       = 2097152 f32
    __bf16* wxh_t = (__bf16*)(zp + (size_t)ZKS * BB * N4D);   // 2048*2816 bf16 = 11.5 MB
    float* spart = (float*)(wxh_t + (size_t)N4D * KLSTM);     // 8*16384 f32 = 512 KB
    __bf16* wpt  = (__bf16*)(spart + (size_t)8 * MROWS);      // 10240*512 bf16 = 10.5 MB
    // w2t (512x2048 bf16 = 2 MB) aliases ctx: consumed by k_score BEFORE k_context writes ctx
    __bf16* w2t  = (__bf16*)ctx;

    hipLaunchKernelGGL(k_wt,      dim3(11776),               dim3(256), 0, stream,
                       w2, wx, wh, wp, w2t, wxh_t, wpt);
    hipLaunchKernelGGL(k_q,       dim3(BB),                  dim3(256), 0, stream, hidden, w1, b1, b2, qq);
    hipLaunchKernelGGL(k_score,   dim3(2048),                dim3(256), 0, stream, enc, w2t, qq, vvec, spart);
    hipLaunchKernelGGL(k_context, dim3(2, BB),               dim3(256), 0, stream, enc, spart, bv, ctx);
    hipLaunchKernelGGL(k_z,       dim3(N4D / 256, BB / 32, ZKS), dim3(256), 0, stream, ctx, emb, cidx, hidden, wxh_t, zp);
    hipLaunchKernelGGL(k_gates,   dim3(BB),                  dim3(256), 0, stream, zp, carry, bl, hout, cout);
    hipLaunchKernelGGL(k_logits,  dim3(320),                 dim3(256), 0, stream, hout, wpt, bp, logits);
}

// Round 18
// 184.192 us; speedup vs baseline: 1.3232x; 1.3232x over previous
//
#include <hip/hip_runtime.h>
#include <hip/hip_bf16.h>
#include <math.h>

#define BB 256
#define TT 64
#define EE 2048
#define DD 512
#define AA 512
#define VV 10000
#define VPAD 10240               // 80 * 128
#define EMBD 256
#define KLSTM (EE + EMBD + DD)   // 2816
#define N4D (4 * DD)             // 2048
#define MROWS (BB * TT)          // 16384

using bf16x8 = __attribute__((ext_vector_type(8))) __bf16;
using f32x4  = __attribute__((ext_vector_type(4))) float;

#define GLL16(gp, lp) __builtin_amdgcn_global_load_lds( \
    (const __attribute__((address_space(1))) void*)(gp), \
    (__attribute__((address_space(3))) void*)(lp), 16, 0, 0)

__device__ __forceinline__ float sigf(float x) { return 1.f / (1.f + expf(-x)); }

// ======== fused weight transposes: w2t | wxh_t | wpt (register-uniform) ========
// [0,1024)     : w2t[n][k]  = bf16(w2[k][n])        64 x 16 tiles
// [1024,6656)  : wxh_t[n][k]= bf16([wx;wh][k][n])   88 x 64 tiles
// [6656,11776) : wpt[n][k]  = bf16(wp[k][n])        16 x 320 tiles (n clamped)
__global__ void k_wt(const float* __restrict__ w2, const float* __restrict__ wx,
                     const float* __restrict__ wh, const float* __restrict__ wp,
                     __bf16* __restrict__ w2t, __bf16* __restrict__ wxh_t,
                     __bf16* __restrict__ wpt) {
    __shared__ float t[32][33];
    const int bid = blockIdx.x;
    const int tid = threadIdx.x;
    const int tx = tid & 31, ty = tid >> 5;   // 32 x 8

    if (bid < 1024) {                         // ---- w2t ----
        const int k0 = (bid & 63) * 32, n0 = (bid >> 6) * 32;
        #pragma unroll
        for (int i = 0; i < 4; ++i)
            t[ty + 8 * i][tx] = w2[(size_t)(k0 + ty + 8 * i) * AA + n0 + tx];
        __syncthreads();
        #pragma unroll
        for (int i = 0; i < 4; ++i)
            w2t[(size_t)(n0 + ty + 8 * i) * EE + k0 + tx] = (__bf16)t[tx][ty + 8 * i];
    } else if (bid < 6656) {                  // ---- wxh_t ----
        const int idx = bid - 1024;
        const int k0 = (idx % 88) * 32, n0 = (idx / 88) * 32;
        #pragma unroll
        for (int i = 0; i < 4; ++i) {
            int k = k0 + ty + 8 * i;
            const float* wrow = (k < EE + EMBD) ? &wx[(size_t)k * N4D]
                                                : &wh[(size_t)(k - EE - EMBD) * N4D];
            t[ty + 8 * i][tx] = wrow[n0 + tx];
        }
        __syncthreads();
        #pragma unroll
        for (int i = 0; i < 4; ++i)
            wxh_t[(size_t)(n0 + ty + 8 * i) * KLSTM + k0 + tx] = (__bf16)t[tx][ty + 8 * i];
    } else {                                  // ---- wpt ----
        const int idx = bid - 6656;
        const int k0 = (idx & 15) * 32, n0 = (idx >> 4) * 32;
        #pragma unroll
        for (int i = 0; i < 4; ++i) {
            int n = n0 + tx;
            t[ty + 8 * i][tx] = wp[(size_t)(k0 + ty + 8 * i) * VV + (n < VV ? n : VV - 1)];
        }
        __syncthreads();
        #pragma unroll
        for (int i = 0; i < 4; ++i)
            wpt[(size_t)(n0 + ty + 8 * i) * DD + k0 + tx] = (__bf16)t[tx][ty + 8 * i];
    }
}

// ---------------- q = hidden @ w1 + b1 + b2 (separate: own regalloc) ----------------
__global__ void k_q(const float* __restrict__ hidden, const float* __restrict__ w1,
                    const float* __restrict__ b1, const float* __restrict__ b2,
                    float* __restrict__ qq) {
    __shared__ float hs[DD];
    const int b = blockIdx.x, tid = threadIdx.x;
    {
        float2 hv = *(const float2*)&hidden[(size_t)b * DD + 2 * tid];
        hs[2 * tid] = hv.x; hs[2 * tid + 1] = hv.y;
    }
    __syncthreads();
    const int a0 = 2 * tid;
    float2 acc = {0.f, 0.f};
    #pragma unroll 4
    for (int k = 0; k < DD; ++k) {
        float2 w = *(const float2*)&w1[(size_t)k * AA + a0];
        float h = hs[k];
        acc.x = fmaf(h, w.x, acc.x);
        acc.y = fmaf(h, w.y, acc.y);
    }
    qq[(size_t)b * AA + a0]     = acc.x + b1[a0]     + b2[a0];
    qq[(size_t)b * AA + a0 + 1] = acc.y + b1[a0 + 1] + b2[a0 + 1];
}

// ---- score partial: spart[nb][m] = sum_{n in nb 128-slice} tanh(q+s)*v ----
// Best measured (95.6 us): tile 128M x 128N, K-step 64, 512 thr = 8 waves
// (2 wm x 4 wn; wave 64x32). Grid 512 flat mb-fastest. B via global_load_lds
// (linear dest, pre-swizzled source, swizzled read); A reg-staged. 2 barriers/it.
__global__ __launch_bounds__(512, 2) void k_score(
        const float* __restrict__ enc, const __bf16* __restrict__ w2t,
        const float* __restrict__ qq, const float* __restrict__ vvec,
        float* __restrict__ spart) {
    __shared__ bf16x8 Abuf[128][8];      // 16 KB [row][granule ^ (row&7)]
    __shared__ bf16x8 Bbuf[128][8];      // 16 KB [row][granule], DMA-written linear
    __shared__ float vsv[128], wredL[4][128];
    __shared__ float qsv2[2][128];
    const int tid = threadIdx.x;
    const int mb = blockIdx.x & 127, nb = blockIdx.x >> 7;
    const int m0 = mb * 128, n0 = nb * 128;       // rows span batches 2mb, 2mb+1
    const int l = tid & 63, wv = tid >> 6;        // 8 waves
    const int wm = wv >> 2, wn = wv & 3;          // wave tile: 64 m x 32 n
    const int ar = l & 15, agr = l >> 4;

    if (tid < 256) {
        int i = tid >> 7, col = tid & 127;
        qsv2[i][col] = qq[(size_t)(2 * mb + i) * AA + n0 + col];
    } else if (tid < 384) {
        vsv[tid - 256] = vvec[n0 + tid - 256];
    }

    // A staging: 128 rows x 8 granules, 4 threads/row, 2 granules (16 f32) each
    const int arow = tid >> 2, ag0 = (tid & 3) * 2;
    const float* aptr = enc + (size_t)(m0 + arow) * EE + ag0 * 8;

    // B staging: wave wv, DMA i in {0,1} covers rows wv*16 + i*8 .. +7 (1 KB each).
    // lane l -> row_off l>>3, stored granule l&7; source granule (l&7)^(l>>3).
    const int brow0 = wv * 16;
    const __bf16* bsrc = w2t + (size_t)(n0 + brow0 + (l >> 3)) * EE
                             + ((l & 7) ^ (l >> 3)) * 8;

    f32x4 acc[4][2];
    #pragma unroll
    for (int mi = 0; mi < 4; ++mi)
        #pragma unroll
        for (int ni = 0; ni < 2; ++ni)
            acc[mi][ni] = (f32x4){0.f, 0.f, 0.f, 0.f};

    const int NIT = EE / 64;   // 32
    for (int it = 0; it < NIT; ++it) {
        if (it > 0) __syncthreads();           // previous tile fully consumed
        // B: 2 async 1KB DMAs per wave (16 total = 128x64 tile)
        #pragma unroll
        for (int i = 0; i < 2; ++i)
            GLL16(bsrc + (size_t)i * 8 * EE + it * 64, &Bbuf[brow0 + i * 8][0]);
        // A: 4 float4 -> 2 swizzled granules
        {
            float4 u0 = *(const float4*)(aptr + it * 64);
            float4 u1 = *(const float4*)(aptr + it * 64 + 4);
            float4 u2 = *(const float4*)(aptr + it * 64 + 8);
            float4 u3 = *(const float4*)(aptr + it * 64 + 12);
            bf16x8 pk;
            pk[0] = (__bf16)u0.x; pk[1] = (__bf16)u0.y; pk[2] = (__bf16)u0.z; pk[3] = (__bf16)u0.w;
            pk[4] = (__bf16)u1.x; pk[5] = (__bf16)u1.y; pk[6] = (__bf16)u1.z; pk[7] = (__bf16)u1.w;
            Abuf[arow][ag0 ^ (arow & 7)] = pk;
            pk[0] = (__bf16)u2.x; pk[1] = (__bf16)u2.y; pk[2] = (__bf16)u2.z; pk[3] = (__bf16)u2.w;
            pk[4] = (__bf16)u3.x; pk[5] = (__bf16)u3.y; pk[6] = (__bf16)u3.z; pk[7] = (__bf16)u3.w;
            Abuf[arow][(ag0 + 1) ^ (arow & 7)] = pk;
        }
        __syncthreads();                       // drains DMA vmcnt + lgkm
        #pragma unroll
        for (int ks = 0; ks < 2; ++ks) {
            bf16x8 afr[4], bfr[2];
            #pragma unroll
            for (int mi = 0; mi < 4; ++mi)
                afr[mi] = Abuf[wm * 64 + mi * 16 + ar][(ks * 4 + agr) ^ (ar & 7)];
            #pragma unroll
            for (int ni = 0; ni < 2; ++ni)
                bfr[ni] = Bbuf[wn * 32 + ni * 16 + ar][(ks * 4 + agr) ^ (ar & 7)];
            #pragma unroll
            for (int mi = 0; mi < 4; ++mi)
                #pragma unroll
                for (int ni = 0; ni < 2; ++ni)
                    acc[mi][ni] = __builtin_amdgcn_mfma_f32_16x16x32_bf16(afr[mi], bfr[ni], acc[mi][ni], 0, 0, 0);
        }
    }

    // epilogue: tanh(q + s) * v, reduce over this block's 128 n-cols
    float sred[4][4];
    #pragma unroll
    for (int mi = 0; mi < 4; ++mi)
        #pragma unroll
        for (int r = 0; r < 4; ++r) sred[mi][r] = 0.f;
    #pragma unroll
    for (int ni = 0; ni < 2; ++ni) {
        const int col = wn * 32 + ni * 16 + ar;
        const float va = vsv[col];
        const float qa = qsv2[wm][col];        // wave's rows all in batch wm
        #pragma unroll
        for (int mi = 0; mi < 4; ++mi)
            #pragma unroll
            for (int r = 0; r < 4; ++r)
                sred[mi][r] += tanhf(qa + acc[mi][ni][r]) * va;
    }
    #pragma unroll
    for (int mi = 0; mi < 4; ++mi)
        #pragma unroll
        for (int r = 0; r < 4; ++r) {
            #pragma unroll
            for (int off = 1; off < 16; off <<= 1)
                sred[mi][r] += __shfl_xor(sred[mi][r], off, 64);
        }
    if (ar == 0) {
        #pragma unroll
        for (int mi = 0; mi < 4; ++mi)
            #pragma unroll
            for (int r = 0; r < 4; ++r)
                wredL[wn][wm * 64 + mi * 16 + agr * 4 + r] = sred[mi][r];
    }
    __syncthreads();
    if (tid < 128)
        spart[(size_t)nb * MROWS + m0 + tid] =
            wredL[0][tid] + wredL[1][tid] + wredL[2][tid] + wredL[3][tid];
}

// -------- softmax over t (from 4 partials) + context = sum_t attn * enc --------
__global__ void k_context(const float* __restrict__ enc, const float* __restrict__ spart,
                          const float* __restrict__ bv, float* __restrict__ ctx) {
    __shared__ float attn[TT];
    const int b = blockIdx.y;
    const int tid = threadIdx.x;
    if (tid < 64) {
        const int m = b * TT + tid;
        float s = spart[m] + spart[MROWS + m] + spart[2 * MROWS + m] + spart[3 * MROWS + m] + bv[0];
        float mx = s;
        #pragma unroll
        for (int off = 1; off < 64; off <<= 1) mx = fmaxf(mx, __shfl_xor(mx, off, 64));
        float p = expf(s - mx);
        float sum = p;
        #pragma unroll
        for (int off = 1; off < 64; off <<= 1) sum += __shfl_xor(sum, off, 64);
        attn[tid] = p / sum;
    }
    __syncthreads();
    const int e = blockIdx.x * 1024 + tid * 4;
    const float* encb = enc + (size_t)b * TT * EE + e;
    float4 acc = {0.f, 0.f, 0.f, 0.f};
    #pragma unroll 4
    for (int t = 0; t < TT; ++t) {
        float a = attn[t];
        float4 ev = *(const float4*)&encb[(size_t)t * EE];
        acc.x = fmaf(a, ev.x, acc.x);
        acc.y = fmaf(a, ev.y, acc.y);
        acc.z = fmaf(a, ev.z, acc.z);
        acc.w = fmaf(a, ev.w, acc.w);
    }
    *(float4*)&ctx[(size_t)b * EE + e] = acc;
}

// ------- z = [ctx, emb[c], hidden] @ [wx; wh] via bf16 MFMA, K split 4 ways -------
#define ZKS 4
#define ZKC (KLSTM / ZKS)    // 704
#define ZNIT (ZKC / 32)      // 22
__global__ void k_z(const float* __restrict__ ctx, const float* __restrict__ emb,
                    const int* __restrict__ cidx, const float* __restrict__ hidden,
                    const __bf16* __restrict__ wt, float* __restrict__ zp) {
    __shared__ bf16x8 Abuf[32][ZKC / 8];   // [row][granule], granule ^= row&7 (45 KB)
    __shared__ int cbs[32];
    const int tid = threadIdx.x;
    const int l = tid & 63, wv = tid >> 6;
    const int b0  = blockIdx.y * 32;
    const int kc0 = blockIdx.z * ZKC;
    const int nw  = blockIdx.x * 256 + wv * 64;

    if (tid < 32) cbs[tid] = cidx[b0 + tid];
    __syncthreads();

    {
        const int srow = tid >> 3, g0 = tid & 7;
        const int bg = b0 + srow;
        const int erow = cbs[srow];
        #pragma unroll
        for (int i = 0; i < 11; ++i) {
            int g = g0 + 8 * i;
            int k = kc0 + g * 8;
            const float* src;
            if (k < EE)             src = &ctx[(size_t)bg * EE + k];
            else if (k < EE + EMBD) src = &emb[(size_t)erow * EMBD + (k - EE)];
            else                    src = &hidden[(size_t)bg * DD + (k - EE - EMBD)];
            float4 u0 = *(const float4*)src;
            float4 u1 = *(const float4*)(src + 4);
            bf16x8 pk;
            pk[0] = (__bf16)u0.x; pk[1] = (__bf16)u0.y; pk[2] = (__bf16)u0.z; pk[3] = (__bf16)u0.w;
            pk[4] = (__bf16)u1.x; pk[5] = (__bf16)u1.y; pk[6] = (__bf16)u1.z; pk[7] = (__bf16)u1.w;
            Abuf[srow][g ^ (srow & 7)] = pk;
        }
    }
    __syncthreads();

    const int ar = l & 15, agr = l >> 4;
    const __bf16* bbase = wt + (size_t)(nw + ar) * KLSTM + kc0 + agr * 8;

    f32x4 acc[2][4];
    #pragma unroll
    for (int mt = 0; mt < 2; ++mt)
        #pragma unroll
        for (int f = 0; f < 4; ++f)
            acc[mt][f] = (f32x4){0.f, 0.f, 0.f, 0.f};

    bf16x8 bA[4], bBv[4];
    #pragma unroll
    for (int f = 0; f < 4; ++f)
        bA[f] = *(const bf16x8*)(bbase + (size_t)f * 16 * KLSTM);

    for (int itp = 0; itp < ZNIT / 2; ++itp) {
        const int it0 = 2 * itp, it1 = 2 * itp + 1;
        #pragma unroll
        for (int f = 0; f < 4; ++f)
            bBv[f] = *(const bf16x8*)(bbase + (size_t)f * 16 * KLSTM + it1 * 32);
        {
            bf16x8 a0 = Abuf[ar][(it0 * 4 + agr) ^ (ar & 7)];
            bf16x8 a1 = Abuf[16 + ar][(it0 * 4 + agr) ^ (ar & 7)];
            #pragma unroll
            for (int f = 0; f < 4; ++f) {
                acc[0][f] = __builtin_amdgcn_mfma_f32_16x16x32_bf16(a0, bA[f], acc[0][f], 0, 0, 0);
                acc[1][f] = __builtin_amdgcn_mfma_f32_16x16x32_bf16(a1, bA[f], acc[1][f], 0, 0, 0);
            }
        }
        const int it2 = (it1 + 1 < ZNIT) ? it1 + 1 : it1;
        #pragma unroll
        for (int f = 0; f < 4; ++f)
            bA[f] = *(const bf16x8*)(bbase + (size_t)f * 16 * KLSTM + it2 * 32);
        {
            bf16x8 a0 = Abuf[ar][(it1 * 4 + agr) ^ (ar & 7)];
            bf16x8 a1 = Abuf[16 + ar][(it1 * 4 + agr) ^ (ar & 7)];
            #pragma unroll
            for (int f = 0; f < 4; ++f) {
                acc[0][f] = __builtin_amdgcn_mfma_f32_16x16x32_bf16(a0, bBv[f], acc[0][f], 0, 0, 0);
                acc[1][f] = __builtin_amdgcn_mfma_f32_16x16x32_bf16(a1, bBv[f], acc[1][f], 0, 0, 0);
            }
        }
    }

    float* zpo = zp + (size_t)blockIdx.z * BB * N4D;
    #pragma unroll
    for (int mt = 0; mt < 2; ++mt)
        #pragma unroll
        for (int f = 0; f < 4; ++f)
            #pragma unroll
            for (int r = 0; r < 4; ++r)
                zpo[(size_t)(b0 + mt * 16 + agr * 4 + r) * N4D + nw + f * 16 + ar] = acc[mt][f][r];
}

// ---------------- LSTM gates: sum K-split partials + bias, then activations ----------------
__global__ void k_gates(const float* __restrict__ zp, const float* __restrict__ carry,
                        const float* __restrict__ bl,
                        float* __restrict__ hout, float* __restrict__ cout) {
    const int b = blockIdx.x, tid = threadIdx.x;
    const size_t P = (size_t)BB * N4D;
    #pragma unroll
    for (int r = 0; r < 2; ++r) {
        int d = tid + r * 256;
        float zi = bl[d], zf = bl[DD + d], zg = bl[2 * DD + d], zo = bl[3 * DD + d];
        #pragma unroll
        for (int ks = 0; ks < ZKS; ++ks) {
            const float* zb = zp + ks * P + (size_t)b * N4D;
            zi += zb[d];
            zf += zb[DD + d];
            zg += zb[2 * DD + d];
            zo += zb[3 * DD + d];
        }
        float c = carry[(size_t)b * DD + d];
        float cn = sigf(zf) * c + sigf(zi) * tanhf(zg);
        float hn = sigf(zo) * tanhf(cn);
        cout[(size_t)b * DD + d] = cn;
        hout[(size_t)b * DD + d] = hn;
    }
}

// ---------------- logits = h_new @ wp + bp  via bf16 MFMA ----------------
__global__ __launch_bounds__(256, 4) void k_logits(
        const float* __restrict__ hnew, const __bf16* __restrict__ wpt,
        const float* __restrict__ bp, float* __restrict__ logits) {
    __shared__ bf16x8 Abuf[64][8];
    __shared__ bf16x8 Bbuf[128][8];
    __shared__ float bps[128];
    const int tid = threadIdx.x;
    const int nb = blockIdx.x % 80, mb = blockIdx.x / 80;
    const int m0 = mb * 64, n0 = nb * 128;
    const int l = tid & 63, wv = tid >> 6;
    const int wm = wv >> 1, wn = wv & 1;
    const int ar = l & 15, agr = l >> 4;

    if (tid < 128) {
        int j = n0 + tid;
        bps[tid] = (j < VV) ? bp[j] : 0.f;
    }

    const int arow = tid >> 2, ag0 = (tid & 3) * 2;
    const float* aptr = hnew + (size_t)(m0 + arow) * DD + ag0 * 8;
    const int brow = tid >> 1, bg0 = (tid & 1) * 4;
    const __bf16* bptr = wpt + (size_t)(n0 + brow) * DD + bg0 * 8;

    f32x4 acc[2][4];
    #pragma unroll
    for (int mi = 0; mi < 2; ++mi)
        #pragma unroll
        for (int ni = 0; ni < 4; ++ni)
            acc[mi][ni] = (f32x4){0.f, 0.f, 0.f, 0.f};

    float4 af[4];
    bf16x8 bstg[4];
    #pragma unroll
    for (int j = 0; j < 4; ++j) af[j] = *(const float4*)(aptr + j * 4);
    #pragma unroll
    for (int i = 0; i < 4; ++i) bstg[i] = *(const bf16x8*)(bptr + i * 8);

    const int NIT = DD / 64;   // 8
    for (int it = 0; it < NIT; ++it) {
        if (it > 0) __syncthreads();
        {
            bf16x8 pk;
            pk[0] = (__bf16)af[0].x; pk[1] = (__bf16)af[0].y; pk[2] = (__bf16)af[0].z; pk[3] = (__bf16)af[0].w;
            pk[4] = (__bf16)af[1].x; pk[5] = (__bf16)af[1].y; pk[6] = (__bf16)af[1].z; pk[7] = (__bf16)af[1].w;
            Abuf[arow][ag0 ^ (arow & 7)] = pk;
            pk[0] = (__bf16)af[2].x; pk[1] = (__bf16)af[2].y; pk[2] = (__bf16)af[2].z; pk[3] = (__bf16)af[2].w;
            pk[4] = (__bf16)af[3].x; pk[5] = (__bf16)af[3].y; pk[6] = (__bf16)af[3].z; pk[7] = (__bf16)af[3].w;
            Abuf[arow][(ag0 + 1) ^ (arow & 7)] = pk;
        }
        #pragma unroll
        for (int i = 0; i < 4; ++i)
            Bbuf[brow][(bg0 + i) ^ (brow & 7)] = bstg[i];
        if (it + 1 < NIT) {
            const int k1 = (it + 1) * 64;
            #pragma unroll
            for (int j = 0; j < 4; ++j) af[j] = *(const float4*)(aptr + k1 + j * 4);
            #pragma unroll
            for (int i = 0; i < 4; ++i) bstg[i] = *(const bf16x8*)(bptr + k1 + i * 8);
        }
        __syncthreads();
        #pragma unroll
        for (int ks = 0; ks < 2; ++ks) {
            bf16x8 afr[2], bfr[4];
            #pragma unroll
            for (int mi = 0; mi < 2; ++mi)
                afr[mi] = Abuf[wm * 32 + mi * 16 + ar][(ks * 4 + agr) ^ (ar & 7)];
            #pragma unroll
            for (int ni = 0; ni < 4; ++ni)
                bfr[ni] = Bbuf[wn * 64 + ni * 16 + ar][(ks * 4 + agr) ^ (ar & 7)];
            #pragma unroll
            for (int mi = 0; mi < 2; ++mi)
                #pragma unroll
                for (int ni = 0; ni < 4; ++ni)
                    acc[mi][ni] = __builtin_amdgcn_mfma_f32_16x16x32_bf16(afr[mi], bfr[ni], acc[mi][ni], 0, 0, 0);
        }
    }

    #pragma unroll
    for (int mi = 0; mi < 2; ++mi)
        #pragma unroll
        for (int ni = 0; ni < 4; ++ni) {
            const int colL = wn * 64 + ni * 16 + ar;
            const int col = n0 + colL;
            if (col < VV) {
                const float bb = bps[colL];
                #pragma unroll
                for (int r = 0; r < 4; ++r) {
                    const int row = m0 + wm * 32 + mi * 16 + agr * 4 + r;
                    logits[(size_t)row * VV + col] = acc[mi][ni][r] + bb;
                }
            }
        }
}

extern "C" void kernel_launch(void* const* d_in, const int* in_sizes, int n_in,
                              void* d_out, int out_size, void* d_ws, size_t ws_size,
                              hipStream_t stream) {
    const int*   cidx   = (const int*)d_in[0];
    const float* hidden = (const float*)d_in[1];
    const float* carry  = (const float*)d_in[2];
    const float* enc    = (const float*)d_in[3];
    const float* emb    = (const float*)d_in[4];
    const float* w1     = (const float*)d_in[5];
    const float* b1     = (const float*)d_in[6];
    const float* w2     = (const float*)d_in[7];
    const float* b2     = (const float*)d_in[8];
    const float* vvec   = (const float*)d_in[9];
    const float* bv     = (const float*)d_in[10];
    const float* wx     = (const float*)d_in[11];
    const float* wh     = (const float*)d_in[12];
    const float* bl     = (const float*)d_in[13];
    const float* wp     = (const float*)d_in[14];
    const float* bp     = (const float*)d_in[15];

    float* out    = (float*)d_out;
    float* logits = out;
    float* hout   = out + (size_t)BB * VV;
    float* cout   = hout + (size_t)BB * DD;

    float* ws    = (float*)d_ws;
    float* qq    = ws;                          // B*A            = 131072 f32
    float* score = qq + (size_t)BB * AA;        // (layout keep)
    float* ctx   = score + (size_t)BB * TT;     // B*E            = 524288 f32
    float* zp    = ctx + (size_t)BB * EE;       // ZKS*B*4D       = 2097152 f32
    __bf16* wxh_t = (__bf16*)(zp + (size_t)ZKS * BB * N4D);   // 2048*2816 bf16 = 11.5 MB
    float* spart = (float*)(wxh_t + (size_t)N4D * KLSTM);     // 4*16384 f32
    __bf16* wpt  = (__bf16*)(spart + (size_t)4 * MROWS);      // 10240*512 bf16 = 10.5 MB
    // w2t (512x2048 bf16 = 2 MB) aliases ctx: consumed by k_score BEFORE k_context writes ctx
    __bf16* w2t  = (__bf16*)ctx;

    hipLaunchKernelGGL(k_wt,      dim3(11776),               dim3(256), 0, stream,
                       w2, wx, wh, wp, w2t, wxh_t, wpt);
    hipLaunchKernelGGL(k_q,       dim3(BB),                  dim3(256), 0, stream, hidden, w1, b1, b2, qq);
    hipLaunchKernelGGL(k_score,   dim3(512),                 dim3(512), 0, stream, enc, w2t, qq, vvec, spart);
    hipLaunchKernelGGL(k_context, dim3(2, BB),               dim3(256), 0, stream, enc, spart, bv, ctx);
    hipLaunchKernelGGL(k_z,       dim3(N4D / 256, BB / 32, ZKS), dim3(256), 0, stream, ctx, emb, cidx, hidden, wxh_t, zp);
    hipLaunchKernelGGL(k_gates,   dim3(BB),                  dim3(256), 0, stream, zp, carry, bl, hout, cout);
    hipLaunchKernelGGL(k_logits,  dim3(320),                 dim3(256), 0, stream, hout, wpt, bp, logits);
}

// Round 19
// 166.911 us; speedup vs baseline: 1.4602x; 1.1035x over previous
//
#include <hip/hip_runtime.h>
#include <hip/hip_bf16.h>
#include <math.h>

#define BB 256
#define TT 64
#define EE 2048
#define DD 512
#define AA 512
#define VV 10000
#define VPAD 10240               // 80 * 128
#define EMBD 256
#define KLSTM (EE + EMBD + DD)   // 2816
#define N4D (4 * DD)             // 2048
#define MROWS (BB * TT)          // 16384

using bf16x8 = __attribute__((ext_vector_type(8))) __bf16;
using f32x4  = __attribute__((ext_vector_type(4))) float;

#define GLL16(gp, lp) __builtin_amdgcn_global_load_lds( \
    (const __attribute__((address_space(1))) void*)(gp), \
    (__attribute__((address_space(3))) void*)(lp), 16, 0, 0)

__device__ __forceinline__ float sigf(float x) { return 1.f / (1.f + expf(-x)); }

// ======== fused weight transposes: w2t | wxh_t | wpt (register-uniform) ========
__global__ void k_wt(const float* __restrict__ w2, const float* __restrict__ wx,
                     const float* __restrict__ wh, const float* __restrict__ wp,
                     __bf16* __restrict__ w2t, __bf16* __restrict__ wxh_t,
                     __bf16* __restrict__ wpt) {
    __shared__ float t[32][33];
    const int bid = blockIdx.x;
    const int tid = threadIdx.x;
    const int tx = tid & 31, ty = tid >> 5;   // 32 x 8

    if (bid < 1024) {                         // ---- w2t ----
        const int k0 = (bid & 63) * 32, n0 = (bid >> 6) * 32;
        #pragma unroll
        for (int i = 0; i < 4; ++i)
            t[ty + 8 * i][tx] = w2[(size_t)(k0 + ty + 8 * i) * AA + n0 + tx];
        __syncthreads();
        #pragma unroll
        for (int i = 0; i < 4; ++i)
            w2t[(size_t)(n0 + ty + 8 * i) * EE + k0 + tx] = (__bf16)t[tx][ty + 8 * i];
    } else if (bid < 6656) {                  // ---- wxh_t ----
        const int idx = bid - 1024;
        const int k0 = (idx % 88) * 32, n0 = (idx / 88) * 32;
        #pragma unroll
        for (int i = 0; i < 4; ++i) {
            int k = k0 + ty + 8 * i;
            const float* wrow = (k < EE + EMBD) ? &wx[(size_t)k * N4D]
                                                : &wh[(size_t)(k - EE - EMBD) * N4D];
            t[ty + 8 * i][tx] = wrow[n0 + tx];
        }
        __syncthreads();
        #pragma unroll
        for (int i = 0; i < 4; ++i)
            wxh_t[(size_t)(n0 + ty + 8 * i) * KLSTM + k0 + tx] = (__bf16)t[tx][ty + 8 * i];
    } else {                                  // ---- wpt ----
        const int idx = bid - 6656;
        const int k0 = (idx & 15) * 32, n0 = (idx >> 4) * 32;
        #pragma unroll
        for (int i = 0; i < 4; ++i) {
            int n = n0 + tx;
            t[ty + 8 * i][tx] = wp[(size_t)(k0 + ty + 8 * i) * VV + (n < VV ? n : VV - 1)];
        }
        __syncthreads();
        #pragma unroll
        for (int i = 0; i < 4; ++i)
            wpt[(size_t)(n0 + ty + 8 * i) * DD + k0 + tx] = (__bf16)t[tx][ty + 8 * i];
    }
}

// ---------------- q = hidden @ w1 + b1 + b2 (separate: own regalloc) ----------------
__global__ void k_q(const float* __restrict__ hidden, const float* __restrict__ w1,
                    const float* __restrict__ b1, const float* __restrict__ b2,
                    float* __restrict__ qq) {
    __shared__ float hs[DD];
    const int b = blockIdx.x, tid = threadIdx.x;
    {
        float2 hv = *(const float2*)&hidden[(size_t)b * DD + 2 * tid];
        hs[2 * tid] = hv.x; hs[2 * tid + 1] = hv.y;
    }
    __syncthreads();
    const int a0 = 2 * tid;
    float2 acc = {0.f, 0.f};
    #pragma unroll 4
    for (int k = 0; k < DD; ++k) {
        float2 w = *(const float2*)&w1[(size_t)k * AA + a0];
        float h = hs[k];
        acc.x = fmaf(h, w.x, acc.x);
        acc.y = fmaf(h, w.y, acc.y);
    }
    qq[(size_t)b * AA + a0]     = acc.x + b1[a0]     + b2[a0];
    qq[(size_t)b * AA + a0 + 1] = acc.y + b1[a0 + 1] + b2[a0 + 1];
}

// ---- score partial: spart[nb][m] = sum_{n in nb 128-slice} tanh(q+s)*v ----
// MAX-OCCUPANCY variant of the proven template: SAME 128M x 128N tile, SAME
// grid 512 (mb fastest; blocks c & c+256 share mb), SAME traffic — but 1024
// threads = 16 waves (4x4, wave tile 32x32, acc[2][2]) so 2 blocks/CU give
// 32 waves/CU (hardware max) to interleave the load->barrier->MFMA chain.
__global__ __launch_bounds__(1024, 8) void k_score(
        const float* __restrict__ enc, const __bf16* __restrict__ w2t,
        const float* __restrict__ qq, const float* __restrict__ vvec,
        float* __restrict__ spart) {
    __shared__ bf16x8 Abuf[128][8];      // 16 KB [row][granule ^ (row&7)]
    __shared__ bf16x8 Bbuf[128][8];      // 16 KB [row][granule], DMA-written linear
    __shared__ float vsv[128];
    __shared__ float qsv2[2][128];
    __shared__ float wredL[16][32];      // [wave][local row]
    const int tid = threadIdx.x;         // 0..1023
    const int mb = blockIdx.x & 127, nb = blockIdx.x >> 7;
    const int m0 = mb * 128, n0 = nb * 128;       // rows span batches 2mb, 2mb+1
    const int l = tid & 63, wv = tid >> 6;        // 16 waves
    const int wm = wv >> 2, wn = wv & 3;          // wave tile: 32 m x 32 n
    const int ar = l & 15, agr = l >> 4;

    if (tid < 256) {
        int i = tid >> 7, col = tid & 127;
        qsv2[i][col] = qq[(size_t)(2 * mb + i) * AA + n0 + col];
    } else if (tid < 384) {
        vsv[tid - 256] = vvec[n0 + tid - 256];
    }

    // A staging: 128 rows x 8 granules, 8 threads/row, 1 granule (8 f32) each
    const int arow = tid >> 3, ag = tid & 7;
    const float* aptr = enc + (size_t)(m0 + arow) * EE + ag * 8;

    // B staging: wave wv's single DMA covers rows wv*8 .. wv*8+7 (1 KB).
    // lane l -> row_off l>>3, stored granule l&7; source granule (l&7)^(l>>3).
    const int brow0 = wv * 8;
    const __bf16* bsrc = w2t + (size_t)(n0 + brow0 + (l >> 3)) * EE
                             + ((l & 7) ^ (l >> 3)) * 8;

    f32x4 acc[2][2];
    #pragma unroll
    for (int mi = 0; mi < 2; ++mi)
        #pragma unroll
        for (int ni = 0; ni < 2; ++ni)
            acc[mi][ni] = (f32x4){0.f, 0.f, 0.f, 0.f};

    const int NIT = EE / 64;   // 32
    for (int it = 0; it < NIT; ++it) {
        if (it > 0) __syncthreads();           // previous tile fully consumed
        // B: 1 async 1KB DMA per wave (16 total = 128x64 tile)
        GLL16(bsrc + it * 64, &Bbuf[brow0][0]);
        // A: 2 float4 -> 1 swizzled granule
        {
            float4 u0 = *(const float4*)(aptr + it * 64);
            float4 u1 = *(const float4*)(aptr + it * 64 + 4);
            bf16x8 pk;
            pk[0] = (__bf16)u0.x; pk[1] = (__bf16)u0.y; pk[2] = (__bf16)u0.z; pk[3] = (__bf16)u0.w;
            pk[4] = (__bf16)u1.x; pk[5] = (__bf16)u1.y; pk[6] = (__bf16)u1.z; pk[7] = (__bf16)u1.w;
            Abuf[arow][ag ^ (arow & 7)] = pk;
        }
        __syncthreads();                       // drains DMA vmcnt + lgkm
        #pragma unroll
        for (int ks = 0; ks < 2; ++ks) {
            bf16x8 afr[2], bfr[2];
            #pragma unroll
            for (int mi = 0; mi < 2; ++mi)
                afr[mi] = Abuf[wm * 32 + mi * 16 + ar][(ks * 4 + agr) ^ (ar & 7)];
            #pragma unroll
            for (int ni = 0; ni < 2; ++ni)
                bfr[ni] = Bbuf[wn * 32 + ni * 16 + ar][(ks * 4 + agr) ^ (ar & 7)];
            #pragma unroll
            for (int mi = 0; mi < 2; ++mi)
                #pragma unroll
                for (int ni = 0; ni < 2; ++ni)
                    acc[mi][ni] = __builtin_amdgcn_mfma_f32_16x16x32_bf16(afr[mi], bfr[ni], acc[mi][ni], 0, 0, 0);
        }
    }

    // epilogue: tanh(q + s) * v, reduce over this wave's 32 n-cols
    float sred[2][4];
    #pragma unroll
    for (int mi = 0; mi < 2; ++mi)
        #pragma unroll
        for (int r = 0; r < 4; ++r) sred[mi][r] = 0.f;
    #pragma unroll
    for (int ni = 0; ni < 2; ++ni) {
        const int col = wn * 32 + ni * 16 + ar;
        const float va = vsv[col];
        const float qa = qsv2[wm >> 1][col];   // wave's rows all in batch wm>>1
        #pragma unroll
        for (int mi = 0; mi < 2; ++mi)
            #pragma unroll
            for (int r = 0; r < 4; ++r)
                sred[mi][r] += tanhf(qa + acc[mi][ni][r]) * va;
    }
    #pragma unroll
    for (int mi = 0; mi < 2; ++mi)
        #pragma unroll
        for (int r = 0; r < 4; ++r) {
            #pragma unroll
            for (int off = 1; off < 16; off <<= 1)
                sred[mi][r] += __shfl_xor(sred[mi][r], off, 64);
        }
    if (ar == 0) {
        #pragma unroll
        for (int mi = 0; mi < 2; ++mi)
            #pragma unroll
            for (int r = 0; r < 4; ++r)
                wredL[wv][mi * 16 + agr * 4 + r] = sred[mi][r];
    }
    __syncthreads();
    if (tid < 128) {
        const int wm4 = tid >> 5, rloc = tid & 31;
        float s = wredL[wm4 * 4 + 0][rloc] + wredL[wm4 * 4 + 1][rloc]
                + wredL[wm4 * 4 + 2][rloc] + wredL[wm4 * 4 + 3][rloc];
        spart[(size_t)nb * MROWS + m0 + tid] = s;
    }
}

// -------- softmax over t (from 4 partials) + context = sum_t attn * enc --------
__global__ void k_context(const float* __restrict__ enc, const float* __restrict__ spart,
                          const float* __restrict__ bv, float* __restrict__ ctx) {
    __shared__ float attn[TT];
    const int b = blockIdx.y;
    const int tid = threadIdx.x;
    if (tid < 64) {
        const int m = b * TT + tid;
        float s = spart[m] + spart[MROWS + m] + spart[2 * MROWS + m] + spart[3 * MROWS + m] + bv[0];
        float mx = s;
        #pragma unroll
        for (int off = 1; off < 64; off <<= 1) mx = fmaxf(mx, __shfl_xor(mx, off, 64));
        float p = expf(s - mx);
        float sum = p;
        #pragma unroll
        for (int off = 1; off < 64; off <<= 1) sum += __shfl_xor(sum, off, 64);
        attn[tid] = p / sum;
    }
    __syncthreads();
    const int e = blockIdx.x * 1024 + tid * 4;
    const float* encb = enc + (size_t)b * TT * EE + e;
    float4 acc = {0.f, 0.f, 0.f, 0.f};
    #pragma unroll 4
    for (int t = 0; t < TT; ++t) {
        float a = attn[t];
        float4 ev = *(const float4*)&encb[(size_t)t * EE];
        acc.x = fmaf(a, ev.x, acc.x);
        acc.y = fmaf(a, ev.y, acc.y);
        acc.z = fmaf(a, ev.z, acc.z);
        acc.w = fmaf(a, ev.w, acc.w);
    }
    *(float4*)&ctx[(size_t)b * EE + e] = acc;
}

// ------- z = [ctx, emb[c], hidden] @ [wx; wh] via bf16 MFMA, K split 4 ways -------
#define ZKS 4
#define ZKC (KLSTM / ZKS)    // 704
#define ZNIT (ZKC / 32)      // 22
__global__ void k_z(const float* __restrict__ ctx, const float* __restrict__ emb,
                    const int* __restrict__ cidx, const float* __restrict__ hidden,
                    const __bf16* __restrict__ wt, float* __restrict__ zp) {
    __shared__ bf16x8 Abuf[32][ZKC / 8];   // [row][granule], granule ^= row&7 (45 KB)
    __shared__ int cbs[32];
    const int tid = threadIdx.x;
    const int l = tid & 63, wv = tid >> 6;
    const int b0  = blockIdx.y * 32;
    const int kc0 = blockIdx.z * ZKC;
    const int nw  = blockIdx.x * 256 + wv * 64;

    if (tid < 32) cbs[tid] = cidx[b0 + tid];
    __syncthreads();

    {
        const int srow = tid >> 3, g0 = tid & 7;
        const int bg = b0 + srow;
        const int erow = cbs[srow];
        #pragma unroll
        for (int i = 0; i < 11; ++i) {
            int g = g0 + 8 * i;
            int k = kc0 + g * 8;
            const float* src;
            if (k < EE)             src = &ctx[(size_t)bg * EE + k];
            else if (k < EE + EMBD) src = &emb[(size_t)erow * EMBD + (k - EE)];
            else                    src = &hidden[(size_t)bg * DD + (k - EE - EMBD)];
            float4 u0 = *(const float4*)src;
            float4 u1 = *(const float4*)(src + 4);
            bf16x8 pk;
            pk[0] = (__bf16)u0.x; pk[1] = (__bf16)u0.y; pk[2] = (__bf16)u0.z; pk[3] = (__bf16)u0.w;
            pk[4] = (__bf16)u1.x; pk[5] = (__bf16)u1.y; pk[6] = (__bf16)u1.z; pk[7] = (__bf16)u1.w;
            Abuf[srow][g ^ (srow & 7)] = pk;
        }
    }
    __syncthreads();

    const int ar = l & 15, agr = l >> 4;
    const __bf16* bbase = wt + (size_t)(nw + ar) * KLSTM + kc0 + agr * 8;

    f32x4 acc[2][4];
    #pragma unroll
    for (int mt = 0; mt < 2; ++mt)
        #pragma unroll
        for (int f = 0; f < 4; ++f)
            acc[mt][f] = (f32x4){0.f, 0.f, 0.f, 0.f};

    bf16x8 bA[4], bBv[4];
    #pragma unroll
    for (int f = 0; f < 4; ++f)
        bA[f] = *(const bf16x8*)(bbase + (size_t)f * 16 * KLSTM);

    for (int itp = 0; itp < ZNIT / 2; ++itp) {
        const int it0 = 2 * itp, it1 = 2 * itp + 1;
        #pragma unroll
        for (int f = 0; f < 4; ++f)
            bBv[f] = *(const bf16x8*)(bbase + (size_t)f * 16 * KLSTM + it1 * 32);
        {
            bf16x8 a0 = Abuf[ar][(it0 * 4 + agr) ^ (ar & 7)];
            bf16x8 a1 = Abuf[16 + ar][(it0 * 4 + agr) ^ (ar & 7)];
            #pragma unroll
            for (int f = 0; f < 4; ++f) {
                acc[0][f] = __builtin_amdgcn_mfma_f32_16x16x32_bf16(a0, bA[f], acc[0][f], 0, 0, 0);
                acc[1][f] = __builtin_amdgcn_mfma_f32_16x16x32_bf16(a1, bA[f], acc[1][f], 0, 0, 0);
            }
        }
        const int it2 = (it1 + 1 < ZNIT) ? it1 + 1 : it1;
        #pragma unroll
        for (int f = 0; f < 4; ++f)
            bA[f] = *(const bf16x8*)(bbase + (size_t)f * 16 * KLSTM + it2 * 32);
        {
            bf16x8 a0 = Abuf[ar][(it1 * 4 + agr) ^ (ar & 7)];
            bf16x8 a1 = Abuf[16 + ar][(it1 * 4 + agr) ^ (ar & 7)];
            #pragma unroll
            for (int f = 0; f < 4; ++f) {
                acc[0][f] = __builtin_amdgcn_mfma_f32_16x16x32_bf16(a0, bBv[f], acc[0][f], 0, 0, 0);
                acc[1][f] = __builtin_amdgcn_mfma_f32_16x16x32_bf16(a1, bBv[f], acc[1][f], 0, 0, 0);
            }
        }
    }

    float* zpo = zp + (size_t)blockIdx.z * BB * N4D;
    #pragma unroll
    for (int mt = 0; mt < 2; ++mt)
        #pragma unroll
        for (int f = 0; f < 4; ++f)
            #pragma unroll
            for (int r = 0; r < 4; ++r)
                zpo[(size_t)(b0 + mt * 16 + agr * 4 + r) * N4D + nw + f * 16 + ar] = acc[mt][f][r];
}

// ---------------- LSTM gates: sum K-split partials + bias, then activations ----------------
__global__ void k_gates(const float* __restrict__ zp, const float* __restrict__ carry,
                        const float* __restrict__ bl,
                        float* __restrict__ hout, float* __restrict__ cout) {
    const int b = blockIdx.x, tid = threadIdx.x;
    const size_t P = (size_t)BB * N4D;
    #pragma unroll
    for (int r = 0; r < 2; ++r) {
        int d = tid + r * 256;
        float zi = bl[d], zf = bl[DD + d], zg = bl[2 * DD + d], zo = bl[3 * DD + d];
        #pragma unroll
        for (int ks = 0; ks < ZKS; ++ks) {
            const float* zb = zp + ks * P + (size_t)b * N4D;
            zi += zb[d];
            zf += zb[DD + d];
            zg += zb[2 * DD + d];
            zo += zb[3 * DD + d];
        }
        float c = carry[(size_t)b * DD + d];
        float cn = sigf(zf) * c + sigf(zi) * tanhf(zg);
        float hn = sigf(zo) * tanhf(cn);
        cout[(size_t)b * DD + d] = cn;
        hout[(size_t)b * DD + d] = hn;
    }
}

// ---------------- logits = h_new @ wp + bp  via bf16 MFMA ----------------
__global__ __launch_bounds__(256, 4) void k_logits(
        const float* __restrict__ hnew, const __bf16* __restrict__ wpt,
        const float* __restrict__ bp, float* __restrict__ logits) {
    __shared__ bf16x8 Abuf[64][8];
    __shared__ bf16x8 Bbuf[128][8];
    __shared__ float bps[128];
    const int tid = threadIdx.x;
    const int nb = blockIdx.x % 80, mb = blockIdx.x / 80;
    const int m0 = mb * 64, n0 = nb * 128;
    const int l = tid & 63, wv = tid >> 6;
    const int wm = wv >> 1, wn = wv & 1;
    const int ar = l & 15, agr = l >> 4;

    if (tid < 128) {
        int j = n0 + tid;
        bps[tid] = (j < VV) ? bp[j] : 0.f;
    }

    const int arow = tid >> 2, ag0 = (tid & 3) * 2;
    const float* aptr = hnew + (size_t)(m0 + arow) * DD + ag0 * 8;
    const int brow = tid >> 1, bg0 = (tid & 1) * 4;
    const __bf16* bptr = wpt + (size_t)(n0 + brow) * DD + bg0 * 8;

    f32x4 acc[2][4];
    #pragma unroll
    for (int mi = 0; mi < 2; ++mi)
        #pragma unroll
        for (int ni = 0; ni < 4; ++ni)
            acc[mi][ni] = (f32x4){0.f, 0.f, 0.f, 0.f};

    float4 af[4];
    bf16x8 bstg[4];
    #pragma unroll
    for (int j = 0; j < 4; ++j) af[j] = *(const float4*)(aptr + j * 4);
    #pragma unroll
    for (int i = 0; i < 4; ++i) bstg[i] = *(const bf16x8*)(bptr + i * 8);

    const int NIT = DD / 64;   // 8
    for (int it = 0; it < NIT; ++it) {
        if (it > 0) __syncthreads();
        {
            bf16x8 pk;
            pk[0] = (__bf16)af[0].x; pk[1] = (__bf16)af[0].y; pk[2] = (__bf16)af[0].z; pk[3] = (__bf16)af[0].w;
            pk[4] = (__bf16)af[1].x; pk[5] = (__bf16)af[1].y; pk[6] = (__bf16)af[1].z; pk[7] = (__bf16)af[1].w;
            Abuf[arow][ag0 ^ (arow & 7)] = pk;
            pk[0] = (__bf16)af[2].x; pk[1] = (__bf16)af[2].y; pk[2] = (__bf16)af[2].z; pk[3] = (__bf16)af[2].w;
            pk[4] = (__bf16)af[3].x; pk[5] = (__bf16)af[3].y; pk[6] = (__bf16)af[3].z; pk[7] = (__bf16)af[3].w;
            Abuf[arow][(ag0 + 1) ^ (arow & 7)] = pk;
        }
        #pragma unroll
        for (int i = 0; i < 4; ++i)
            Bbuf[brow][(bg0 + i) ^ (brow & 7)] = bstg[i];
        if (it + 1 < NIT) {
            const int k1 = (it + 1) * 64;
            #pragma unroll
            for (int j = 0; j < 4; ++j) af[j] = *(const float4*)(aptr + k1 + j * 4);
            #pragma unroll
            for (int i = 0; i < 4; ++i) bstg[i] = *(const bf16x8*)(bptr + k1 + i * 8);
        }
        __syncthreads();
        #pragma unroll
        for (int ks = 0; ks < 2; ++ks) {
            bf16x8 afr[2], bfr[4];
            #pragma unroll
            for (int mi = 0; mi < 2; ++mi)
                afr[mi] = Abuf[wm * 32 + mi * 16 + ar][(ks * 4 + agr) ^ (ar & 7)];
            #pragma unroll
            for (int ni = 0; ni < 4; ++ni)
                bfr[ni] = Bbuf[wn * 64 + ni * 16 + ar][(ks * 4 + agr) ^ (ar & 7)];
            #pragma unroll
            for (int mi = 0; mi < 2; ++mi)
                #pragma unroll
                for (int ni = 0; ni < 4; ++ni)
                    acc[mi][ni] = __builtin_amdgcn_mfma_f32_16x16x32_bf16(afr[mi], bfr[ni], acc[mi][ni], 0, 0, 0);
        }
    }

    #pragma unroll
    for (int mi = 0; mi < 2; ++mi)
        #pragma unroll
        for (int ni = 0; ni < 4; ++ni) {
            const int colL = wn * 64 + ni * 16 + ar;
            const int col = n0 + colL;
            if (col < VV) {
                const float bb = bps[colL];
                #pragma unroll
                for (int r = 0; r < 4; ++r) {
                    const int row = m0 + wm * 32 + mi * 16 + agr * 4 + r;
                    logits[(size_t)row * VV + col] = acc[mi][ni][r] + bb;
                }
            }
        }
}

extern "C" void kernel_launch(void* const* d_in, const int* in_sizes, int n_in,
                              void* d_out, int out_size, void* d_ws, size_t ws_size,
                              hipStream_t stream) {
    const int*   cidx   = (const int*)d_in[0];
    const float* hidden = (const float*)d_in[1];
    const float* carry  = (const float*)d_in[2];
    const float* enc    = (const float*)d_in[3];
    const float* emb    = (const float*)d_in[4];
    const float* w1     = (const float*)d_in[5];
    const float* b1     = (const float*)d_in[6];
    const float* w2     = (const float*)d_in[7];
    const float* b2     = (const float*)d_in[8];
    const float* vvec   = (const float*)d_in[9];
    const float* bv     = (const float*)d_in[10];
    const float* wx     = (const float*)d_in[11];
    const float* wh     = (const float*)d_in[12];
    const float* bl     = (const float*)d_in[13];
    const float* wp     = (const float*)d_in[14];
    const float* bp     = (const float*)d_in[15];

    float* out    = (float*)d_out;
    float* logits = out;
    float* hout   = out + (size_t)BB * VV;
    float* cout   = hout + (size_t)BB * DD;

    float* ws    = (float*)d_ws;
    float* qq    = ws;                          // B*A            = 131072 f32
    float* score = qq + (size_t)BB * AA;        // (layout keep)
    float* ctx   = score + (size_t)BB * TT;     // B*E            = 524288 f32
    float* zp    = ctx + (size_t)BB * EE;       // ZKS*B*4D       = 2097152 f32
    __bf16* wxh_t = (__bf16*)(zp + (size_t)ZKS * BB * N4D);   // 2048*2816 bf16 = 11.5 MB
    float* spart = (float*)(wxh_t + (size_t)N4D * KLSTM);     // 4*16384 f32
    __bf16* wpt  = (__bf16*)(spart + (size_t)4 * MROWS);      // 10240*512 bf16 = 10.5 MB
    // w2t (512x2048 bf16 = 2 MB) aliases ctx: consumed by k_score BEFORE k_context writes ctx
    __bf16* w2t  = (__bf16*)ctx;

    hipLaunchKernelGGL(k_wt,      dim3(11776),               dim3(256), 0, stream,
                       w2, wx, wh, wp, w2t, wxh_t, wpt);
    hipLaunchKernelGGL(k_q,       dim3(BB),                  dim3(256), 0, stream, hidden, w1, b1, b2, qq);
    hipLaunchKernelGGL(k_score,   dim3(512),                 dim3(1024), 0, stream, enc, w2t, qq, vvec, spart);
    hipLaunchKernelGGL(k_context, dim3(2, BB),               dim3(256), 0, stream, enc, spart, bv, ctx);
    hipLaunchKernelGGL(k_z,       dim3(N4D / 256, BB / 32, ZKS), dim3(256), 0, stream, ctx, emb, cidx, hidden, wxh_t, zp);
    hipLaunchKernelGGL(k_gates,   dim3(BB),                  dim3(256), 0, stream, zp, carry, bl, hout, cout);
    hipLaunchKernelGGL(k_logits,  dim3(320),                 dim3(256), 0, stream, hout, wpt, bp, logits);
}